// Round 12
// baseline (499.380 us; speedup 1.0000x reference)
//
#include <hip/hip_runtime.h>

#define N_TOK 8192
#define D_IN 384
#define D_H 64
#define NHEADS 4
#define NSPLIT 4
#define N_CLS 6
#define LN_EPS 1e-5f

typedef __attribute__((ext_vector_type(8))) short short8;
typedef __attribute__((ext_vector_type(4))) float f32x4;

#define L2E2 2.08136898100560774f   /* (log2 e)^2 */

__device__ __forceinline__ unsigned short f2bf(float f) {
    unsigned int u = __float_as_uint(f);
    u += 0x7FFFu + ((u >> 16) & 1u);          // RNE (finite values only here)
    return (unsigned short)(u >> 16);
}
__device__ __forceinline__ float bf2f(unsigned short s) {
    return __uint_as_float(((unsigned int)s) << 16);
}

// Permuted key position within a 64-key tile (pairs bf16 cols for packed LDS
// writes in flash). P-columns and V-rows share the bijection -> PV invariant.
__device__ __forceinline__ int kperm(int k) {
    return (k & 32) + 2 * (k & 15) + ((k >> 4) & 1);
}

// ---------------------------------------------------------------------------
// Fused stage 1 (r9's proven version) + zeroing of the finisher counters.
// 256 blocks x 512 thr: phase 1: 8 waves x 4 rows -> h in LDS; phase 2:
// wave wv -> head wv>>1, half wv&1 (16 rows). Outputs: hp bf16 coalesced;
// Vf bf16 key-permuted coalesced b128; ssq2 = (sum hp^2)*(log2 e)^2.
// ---------------------------------------------------------------------------
__global__ __launch_bounds__(512) void stage1_kernel(
    const float* __restrict__ x, const float* __restrict__ proj_w,
    const float* __restrict__ proj_b, const float* __restrict__ head_w,
    const float* __restrict__ head_b,
    unsigned short* __restrict__ hp, unsigned short* __restrict__ Vf,
    float* __restrict__ ssq2, int* __restrict__ counters)
{
    const int lane = threadIdx.x & 63;
    const int wv   = threadIdx.x >> 6;       // 0..7
    const int rb0  = blockIdx.x * 32;

    if (blockIdx.x == 0 && threadIdx.x < 64) counters[threadIdx.x] = 0;

    __shared__ float h_sh[32][68];                          // [row][feat]
    __shared__ __align__(16) unsigned short vt[NHEADS][4][64][8];

    // ---- phase 1: h = relu(x @ proj_w + b), 4 rows per wave ----
    {
        float acc[4];
        float b = proj_b[lane];
        #pragma unroll
        for (int r = 0; r < 4; ++r) acc[r] = b;
        const float* x0 = x + (size_t)(rb0 + wv * 4) * D_IN;
        #pragma unroll 2
        for (int k4 = 0; k4 < D_IN / 4; ++k4) {
            float w0 = proj_w[(k4 * 4 + 0) * 64 + lane];
            float w1 = proj_w[(k4 * 4 + 1) * 64 + lane];
            float w2 = proj_w[(k4 * 4 + 2) * 64 + lane];
            float w3 = proj_w[(k4 * 4 + 3) * 64 + lane];
            #pragma unroll
            for (int r = 0; r < 4; ++r) {
                float4 xv = *(const float4*)(x0 + r * D_IN + k4 * 4); // wave-uniform
                acc[r] = fmaf(xv.x, w0, acc[r]);
                acc[r] = fmaf(xv.y, w1, acc[r]);
                acc[r] = fmaf(xv.z, w2, acc[r]);
                acc[r] = fmaf(xv.w, w3, acc[r]);
            }
        }
        #pragma unroll
        for (int r = 0; r < 4; ++r)
            h_sh[wv * 4 + r][lane] = fmaxf(acc[r], 0.f);
    }
    __syncthreads();

    // ---- phase 2: hp = h @ head_w[head] + head_b[head]; 16 rows per wave ----
    const int head = wv >> 1;
    const int half = wv & 1;
    float a[16];
    {
        float b = head_b[head * 64 + lane];
        #pragma unroll
        for (int r = 0; r < 16; ++r) a[r] = b;
    }
    const float* wb = head_w + head * 64 * 64;
    #pragma unroll 2
    for (int e4 = 0; e4 < 16; ++e4) {
        float w0 = wb[(e4 * 4 + 0) * 64 + lane];
        float w1 = wb[(e4 * 4 + 1) * 64 + lane];
        float w2 = wb[(e4 * 4 + 2) * 64 + lane];
        float w3 = wb[(e4 * 4 + 3) * 64 + lane];
        #pragma unroll
        for (int r = 0; r < 16; ++r) {
            float4 hv = *(const float4*)&h_sh[half * 16 + r][e4 * 4]; // uniform b128
            a[r] = fmaf(hv.x, w0, a[r]);
            a[r] = fmaf(hv.y, w1, a[r]);
            a[r] = fmaf(hv.z, w2, a[r]);
            a[r] = fmaf(hv.w, w3, a[r]);
        }
    }

    #pragma unroll
    for (int r = 0; r < 16; ++r) {
        int kl  = half * 16 + r;
        int row = rb0 + kl;
        unsigned short hb = f2bf(a[r]);
        float hf = bf2f(hb);
        hp[((size_t)head * N_TOK + row) * 64 + lane] = hb;
        int p = kperm(row & 63);              // halves write disjoint even/odd
        vt[head][(p >> 3) & 3][lane][p & 7] = hb;
        float s = hf * hf;
        #pragma unroll
        for (int off = 32; off > 0; off >>= 1) s += __shfl_xor(s, off);
        if (lane == 0) ssq2[head * N_TOK + row] = s * L2E2;
    }
    __syncthreads();

    // ---- write Vf coalesced: 1024 chunks of 16B, 2 per thread ----
    const int kgbase = (rb0 & 32) ? 4 : 0;
    #pragma unroll
    for (int i = 0; i < 2; ++i) {
        int c  = threadIdx.x + 512 * i;
        int hc = c >> 8, rem = c & 255;
        int kg = rem >> 6, d = rem & 63;
        short8 v = *(const short8*)&vt[hc][kg][d][0];
        *(short8*)&Vf[(((size_t)hc * (N_TOK / 8) + (rb0 >> 6) * 8 + kgbase + kg) * 64
                       + d) * 8] = v;
    }
}

// ---------------------------------------------------------------------------
// Flash distance-attention (r8 hot loop, proven 173 µs no-spill; skew removed
// — r11 showed it neutral) + FUSED COMBINE FINISHER: the constant ~115 µs
// non-flash residue across r6-r11 is inter-kernel drain/ramp, not work
// (stage1 ~10 µs, combine ~5 µs of actual arithmetic). Each 128-row q-range
// is covered by 16 (head,split) blocks; after its epilogue each block does
// fence + atomicAdd(counter[qblock]); the 16th block acquires and runs the
// combine (head-softmax mix, LN, FC) for those rows in-kernel — third launch
// eliminated. nsplit=4: Og halves to 16 MB, 4096 waves = full 4/SIMD
// residency, ktps=32. Grid (16 combos, 64 q-blocks); combo%8 -> head/XCD.
// ---------------------------------------------------------------------------
__global__ __launch_bounds__(256, 4) void flash_kernel(
    const unsigned short* __restrict__ hp, const unsigned short* __restrict__ Vf,
    const float* __restrict__ ssq2, unsigned short* __restrict__ Og,
    float* __restrict__ Lg, const float* __restrict__ attn_w,
    const float* __restrict__ gamma, const float* __restrict__ beta,
    const float* __restrict__ fc_w, const float* __restrict__ fc_b,
    float* __restrict__ out, int* __restrict__ counters)
{
    const int head  = blockIdx.x & 3;        // combo = split*NHEADS+head
    const int split = blockIdx.x >> 2;
    const int q0    = blockIdx.y * 128;
    const int w     = threadIdx.x >> 6;
    const int lane  = threadIdx.x & 63;
    const int col   = lane & 15;
    const int quad  = lane >> 4;

    __shared__ __align__(16) unsigned short Psh[4][2][16][72];
    __shared__ int is_last;

    const unsigned short* hpH = hp + head * (N_TOK * 64);
    const unsigned short* VfH = Vf + head * (N_TOK * 64);
    const float* ssqH = ssq2 + head * N_TOK;

    const int rb = q0 + w * 32;              // this wave's 32 q-rows

    short8 aQ[2][2];
    float ssqn2[2][4];
    #pragma unroll
    for (int s = 0; s < 2; ++s) {
        const unsigned short* qrow = hpH + (rb + s * 16 + col) * 64;
        aQ[s][0] = *(const short8*)(qrow + quad * 8);
        aQ[s][1] = *(const short8*)(qrow + 32 + quad * 8);
        #pragma unroll
        for (int r = 0; r < 4; ++r)
            ssqn2[s][r] = ssqH[rb + s * 16 + quad * 4 + r];
    }

    const f32x4 zero4 = {0.f, 0.f, 0.f, 0.f};
    f32x4 accO[2][4] = {{zero4, zero4, zero4, zero4}, {zero4, zero4, zero4, zero4}};
    f32x4 accL[2] = {zero4, zero4};
    const short8 ones = {16256,16256,16256,16256,16256,16256,16256,16256}; // bf16 1.0
    const float NEG2L2 = -2.0f * L2E2;

    const int kt0 = split * (N_TOK / 64 / NSPLIT);
    #pragma unroll 1
    for (int kt = kt0; kt < kt0 + N_TOK / 64 / NSPLIT; ++kt) {
        const unsigned short* kb = hpH + kt * 4096;
        const unsigned short* vb = VfH + kt * 4096;

        float sm2[4];
        #pragma unroll
        for (int nt = 0; nt < 4; ++nt) sm2[nt] = ssqH[kt * 64 + nt * 16 + col];

        // ---- half A: S for keys 0..31 (nt 0,1) ----
        f32x4 aSA[2][2] = {{zero4, zero4}, {zero4, zero4}};
        #pragma unroll
        for (int nt = 0; nt < 2; ++nt) {
            const unsigned short* kr = kb + (nt * 16 + col) * 64 + quad * 8;
            short8 b0 = *(const short8*)kr;
            short8 b1 = *(const short8*)(kr + 32);
            aSA[0][nt] = __builtin_amdgcn_mfma_f32_16x16x32_bf16(aQ[0][0], b0, aSA[0][nt], 0, 0, 0);
            aSA[0][nt] = __builtin_amdgcn_mfma_f32_16x16x32_bf16(aQ[0][1], b1, aSA[0][nt], 0, 0, 0);
            aSA[1][nt] = __builtin_amdgcn_mfma_f32_16x16x32_bf16(aQ[1][0], b0, aSA[1][nt], 0, 0, 0);
            aSA[1][nt] = __builtin_amdgcn_mfma_f32_16x16x32_bf16(aQ[1][1], b1, aSA[1][nt], 0, 0, 0);
        }
        // softmax A -> write d0 (cols 0..31); aSA dies here
        #pragma unroll
        for (int s = 0; s < 2; ++s) {
            float pf0[4], pf1[4];
            #pragma unroll
            for (int r = 0; r < 4; ++r) {
                float sq0 = fmaf(aSA[s][0][r], NEG2L2, ssqn2[s][r] + sm2[0]);
                pf0[r] = __builtin_amdgcn_exp2f(-__builtin_amdgcn_sqrtf(fmaxf(sq0, 0.f)));
                float sq1 = fmaf(aSA[s][1][r], NEG2L2, ssqn2[s][r] + sm2[1]);
                pf1[r] = __builtin_amdgcn_exp2f(-__builtin_amdgcn_sqrtf(fmaxf(sq1, 0.f)));
            }
            #pragma unroll
            for (int r = 0; r < 4; ++r) {
                unsigned int d0 = __builtin_amdgcn_perm(__float_as_uint(pf1[r]),
                                                        __float_as_uint(pf0[r]), 0x07060302u);
                *(unsigned int*)&Psh[w][s][quad * 4 + r][2 * col] = d0;
            }
        }

        // ---- half B: S for keys 32..63 (nt 2,3) ----
        f32x4 aSB[2][2] = {{zero4, zero4}, {zero4, zero4}};
        #pragma unroll
        for (int nt = 0; nt < 2; ++nt) {
            const unsigned short* kr = kb + ((nt + 2) * 16 + col) * 64 + quad * 8;
            short8 b0 = *(const short8*)kr;
            short8 b1 = *(const short8*)(kr + 32);
            aSB[0][nt] = __builtin_amdgcn_mfma_f32_16x16x32_bf16(aQ[0][0], b0, aSB[0][nt], 0, 0, 0);
            aSB[0][nt] = __builtin_amdgcn_mfma_f32_16x16x32_bf16(aQ[0][1], b1, aSB[0][nt], 0, 0, 0);
            aSB[1][nt] = __builtin_amdgcn_mfma_f32_16x16x32_bf16(aQ[1][0], b0, aSB[1][nt], 0, 0, 0);
            aSB[1][nt] = __builtin_amdgcn_mfma_f32_16x16x32_bf16(aQ[1][1], b1, aSB[1][nt], 0, 0, 0);
        }

        // bV for c=0 issued here: latency covered by softmax-B (16 regs only)
        short8 bV0[4];
        #pragma unroll
        for (int dt = 0; dt < 4; ++dt)
            bV0[dt] = *(const short8*)(vb + (quad * 64 + dt * 16 + col) * 8);

        // softmax B -> write d1 (cols 32..63)
        #pragma unroll
        for (int s = 0; s < 2; ++s) {
            float pf2[4], pf3[4];
            #pragma unroll
            for (int r = 0; r < 4; ++r) {
                float sq2 = fmaf(aSB[s][0][r], NEG2L2, ssqn2[s][r] + sm2[2]);
                pf2[r] = __builtin_amdgcn_exp2f(-__builtin_amdgcn_sqrtf(fmaxf(sq2, 0.f)));
                float sq3 = fmaf(aSB[s][1][r], NEG2L2, ssqn2[s][r] + sm2[3]);
                pf3[r] = __builtin_amdgcn_exp2f(-__builtin_amdgcn_sqrtf(fmaxf(sq3, 0.f)));
            }
            #pragma unroll
            for (int r = 0; r < 4; ++r) {
                unsigned int d1 = __builtin_amdgcn_perm(__float_as_uint(pf3[r]),
                                                        __float_as_uint(pf2[r]), 0x07060302u);
                *(unsigned int*)&Psh[w][s][quad * 4 + r][32 + 2 * col] = d1;
            }
            // diag tile: force p=1.0 exactly
            int r0 = rb + s * 16;
            if (kt == (r0 >> 6) && lane < 16) {
                int t = (r0 >> 4) & 3;
                Psh[w][s][lane][((t & 2) << 4) + 2 * lane + (t & 1)] = 0x3F80;
            }
        }

        // ---- PV c=0: aP reads, then bV1 issue (covered by c=0 MFMAs) ----
        {
            short8 aP0 = *(const short8*)&Psh[w][0][col][quad * 8];
            short8 aP1 = *(const short8*)&Psh[w][1][col][quad * 8];
            short8 bV1[4];
            #pragma unroll
            for (int dt = 0; dt < 4; ++dt)
                bV1[dt] = *(const short8*)(vb + ((4 + quad) * 64 + dt * 16 + col) * 8);
            accL[0] = __builtin_amdgcn_mfma_f32_16x16x32_bf16(aP0, ones, accL[0], 0, 0, 0);
            accL[1] = __builtin_amdgcn_mfma_f32_16x16x32_bf16(aP1, ones, accL[1], 0, 0, 0);
            #pragma unroll
            for (int dt = 0; dt < 4; ++dt) {
                accO[0][dt] = __builtin_amdgcn_mfma_f32_16x16x32_bf16(aP0, bV0[dt], accO[0][dt], 0, 0, 0);
                accO[1][dt] = __builtin_amdgcn_mfma_f32_16x16x32_bf16(aP1, bV0[dt], accO[1][dt], 0, 0, 0);
            }
            // ---- PV c=1 ----
            short8 aP0b = *(const short8*)&Psh[w][0][col][32 + quad * 8];
            short8 aP1b = *(const short8*)&Psh[w][1][col][32 + quad * 8];
            accL[0] = __builtin_amdgcn_mfma_f32_16x16x32_bf16(aP0b, ones, accL[0], 0, 0, 0);
            accL[1] = __builtin_amdgcn_mfma_f32_16x16x32_bf16(aP1b, ones, accL[1], 0, 0, 0);
            #pragma unroll
            for (int dt = 0; dt < 4; ++dt) {
                accO[0][dt] = __builtin_amdgcn_mfma_f32_16x16x32_bf16(aP0b, bV1[dt], accO[0][dt], 0, 0, 0);
                accO[1][dt] = __builtin_amdgcn_mfma_f32_16x16x32_bf16(aP1b, bV1[dt], accO[1][dt], 0, 0, 0);
            }
        }
    }

    // ---- epilogue: unnormalized O (bf16) and l (f32) for this split ----
    unsigned short* og = Og + (size_t)(split * NHEADS + head) * N_TOK * 64;
    float* lg = Lg + (size_t)(split * NHEADS + head) * N_TOK;
    #pragma unroll
    for (int s = 0; s < 2; ++s)
        #pragma unroll
        for (int r = 0; r < 4; ++r) {
            int row = rb + s * 16 + quad * 4 + r;
            #pragma unroll
            for (int dt = 0; dt < 4; ++dt)
                og[row * 64 + dt * 16 + col] = f2bf(accO[s][dt][r]);
            if (col == 0) lg[row] = accL[s][r];
        }

    // ---- finisher election: 16th (head,split) block for this q-range runs
    //      the combine for rows q0..q0+127 (release/acquire via threadfence).
    __threadfence();
    __syncthreads();
    if (threadIdx.x == 0)
        is_last = (atomicAdd(&counters[blockIdx.y], 1) == NHEADS * NSPLIT - 1);
    __syncthreads();
    if (!is_last) return;
    __threadfence();

    float b0a = attn_w[0], b1a = attn_w[1], b2a = attn_w[2], b3a = attn_w[3];
    float m = fmaxf(fmaxf(b0a, b1a), fmaxf(b2a, b3a));
    float e0 = __expf(b0a - m), e1 = __expf(b1a - m);
    float e2 = __expf(b2a - m), e3 = __expf(b3a - m);
    float inv = 1.f / (e0 + e1 + e2 + e3);
    float aw[4] = {e0 * inv, e1 * inv, e2 * inv, e3 * inv};
    float gam = gamma[lane], bet = beta[lane];

    #pragma unroll 1
    for (int rr = 0; rr < 32; ++rr) {
        int row = q0 + w * 32 + rr;
        float c = 0.f;
        #pragma unroll
        for (int hh = 0; hh < NHEADS; ++hh) {
            float l = 0.f, o = 0.f;
            #pragma unroll
            for (int s = 0; s < NSPLIT; ++s) {
                l += Lg[(s * NHEADS + hh) * N_TOK + row];
                o += bf2f(Og[(size_t)((s * NHEADS + hh) * N_TOK + row) * 64 + lane]);
            }
            c += aw[hh] * o * __builtin_amdgcn_rcpf(l);
        }
        float s = c;
        #pragma unroll
        for (int off = 32; off > 0; off >>= 1) s += __shfl_xor(s, off);
        float mu = s * (1.f / 64.f);
        float d = c - mu;
        float v = d * d;
        #pragma unroll
        for (int off = 32; off > 0; off >>= 1) v += __shfl_xor(v, off);
        float normed = d * rsqrtf(v * (1.f / 64.f) + LN_EPS) * gam + bet;

        #pragma unroll
        for (int cc = 0; cc < N_CLS; ++cc) {
            float p = normed * fc_w[lane * N_CLS + cc];
            #pragma unroll
            for (int off = 32; off > 0; off >>= 1) p += __shfl_xor(p, off);
            if (lane == 0) out[row * N_CLS + cc] = p + fc_b[cc];
        }
    }
}

// ---------------------------------------------------------------------------
extern "C" void kernel_launch(void* const* d_in, const int* in_sizes, int n_in,
                              void* d_out, int out_size, void* d_ws, size_t ws_size,
                              hipStream_t stream)
{
    const float* x      = (const float*)d_in[0];
    const float* proj_w = (const float*)d_in[1];
    const float* proj_b = (const float*)d_in[2];
    const float* head_w = (const float*)d_in[3];
    const float* head_b = (const float*)d_in[4];
    const float* attn_w = (const float*)d_in[5];
    const float* gamma  = (const float*)d_in[6];
    const float* beta   = (const float*)d_in[7];
    const float* fc_w   = (const float*)d_in[8];
    const float* fc_b   = (const float*)d_in[9];
    float* out = (float*)d_out;

    char* ws = (char*)d_ws;
    // ws layout (bytes):
    //   hp       bf16 [4][8192][64]        @ 0            (4 MB)
    //   Vf       bf16 [4][1024][64][8]     @ 4 MB         (4 MB, key-permuted)
    //   ssq2     f32  [4][8192]            @ 8 MB         (128 KB)
    //   Og       bf16 [4][4][8192][64]     @ 8M+128K      (16 MB)
    //   Lg       f32  [4][4][8192]         @ 24M+128K     (512 KB)
    //   counters int  [64]                 @ 24M+640K     (256 B)
    unsigned short* hp = (unsigned short*)(ws);
    unsigned short* Vf = (unsigned short*)(ws + (4u << 20));
    float* ssq2 = (float*)(ws + (8u << 20));
    unsigned short* Og = (unsigned short*)(ws + (8u << 20) + (128u << 10));
    float* Lg   = (float*)(ws + (24u << 20) + (128u << 10));
    int* counters = (int*)(ws + (24u << 20) + (640u << 10));

    stage1_kernel<<<N_TOK / 32, 512, 0, stream>>>(x, proj_w, proj_b, head_w, head_b,
                                                  hp, Vf, ssq2, counters);
    dim3 g2(NHEADS * NSPLIT, N_TOK / 128);  // combo fastest -> one head per XCD
    flash_kernel<<<g2, 256, 0, stream>>>(hp, Vf, ssq2, Og, Lg, attn_w, gamma,
                                         beta, fc_w, fc_b, out, counters);
}

// Round 13
// 274.568 us; speedup vs baseline: 1.8188x; 1.8188x over previous
//
#include <hip/hip_runtime.h>

#define N_TOK 8192
#define D_IN 384
#define D_H 64
#define NHEADS 4
#define NSPLIT 4
#define N_CLS 6
#define LN_EPS 1e-5f

typedef __attribute__((ext_vector_type(8))) short short8;
typedef __attribute__((ext_vector_type(4))) float f32x4;

#define L2E2 2.08136898100560774f   /* (log2 e)^2 */

__device__ __forceinline__ unsigned short f2bf(float f) {
    unsigned int u = __float_as_uint(f);
    u += 0x7FFFu + ((u >> 16) & 1u);          // RNE (finite values only here)
    return (unsigned short)(u >> 16);
}
__device__ __forceinline__ float bf2f(unsigned short s) {
    return __uint_as_float(((unsigned int)s) << 16);
}

// Permuted key position within a 64-key tile (pairs bf16 cols for packed LDS
// writes in flash). P-columns and V-rows share the bijection -> PV invariant.
__device__ __forceinline__ int kperm(int k) {
    return (k & 32) + 2 * (k & 15) + ((k >> 4) & 1);
}

// ---------------------------------------------------------------------------
// Fused stage 1 (r9's proven version). 256 blocks x 512 thr:
// phase 1: 8 waves x 4 rows each -> h in LDS; phase 2: wave wv -> head wv>>1,
// half wv&1 (16 rows). Outputs: hp bf16 coalesced; Vf bf16 key-permuted
// coalesced b128; ssq2 = (sum hp^2)*(log2 e)^2.
// NO cooperative / fence / finisher variants: r10 (grid.sync) and r12
// (per-block threadfence) both flushed L2 device-wide and lost 2-3x.
// ---------------------------------------------------------------------------
__global__ __launch_bounds__(512) void stage1_kernel(
    const float* __restrict__ x, const float* __restrict__ proj_w,
    const float* __restrict__ proj_b, const float* __restrict__ head_w,
    const float* __restrict__ head_b,
    unsigned short* __restrict__ hp, unsigned short* __restrict__ Vf,
    float* __restrict__ ssq2)
{
    const int lane = threadIdx.x & 63;
    const int wv   = threadIdx.x >> 6;       // 0..7
    const int rb0  = blockIdx.x * 32;

    __shared__ float h_sh[32][68];                          // [row][feat]
    __shared__ __align__(16) unsigned short vt[NHEADS][4][64][8];

    // ---- phase 1: h = relu(x @ proj_w + b), 4 rows per wave ----
    {
        float acc[4];
        float b = proj_b[lane];
        #pragma unroll
        for (int r = 0; r < 4; ++r) acc[r] = b;
        const float* x0 = x + (size_t)(rb0 + wv * 4) * D_IN;
        #pragma unroll 2
        for (int k4 = 0; k4 < D_IN / 4; ++k4) {
            float w0 = proj_w[(k4 * 4 + 0) * 64 + lane];
            float w1 = proj_w[(k4 * 4 + 1) * 64 + lane];
            float w2 = proj_w[(k4 * 4 + 2) * 64 + lane];
            float w3 = proj_w[(k4 * 4 + 3) * 64 + lane];
            #pragma unroll
            for (int r = 0; r < 4; ++r) {
                float4 xv = *(const float4*)(x0 + r * D_IN + k4 * 4); // wave-uniform
                acc[r] = fmaf(xv.x, w0, acc[r]);
                acc[r] = fmaf(xv.y, w1, acc[r]);
                acc[r] = fmaf(xv.z, w2, acc[r]);
                acc[r] = fmaf(xv.w, w3, acc[r]);
            }
        }
        #pragma unroll
        for (int r = 0; r < 4; ++r)
            h_sh[wv * 4 + r][lane] = fmaxf(acc[r], 0.f);
    }
    __syncthreads();

    // ---- phase 2: hp = h @ head_w[head] + head_b[head]; 16 rows per wave ----
    const int head = wv >> 1;
    const int half = wv & 1;
    float a[16];
    {
        float b = head_b[head * 64 + lane];
        #pragma unroll
        for (int r = 0; r < 16; ++r) a[r] = b;
    }
    const float* wb = head_w + head * 64 * 64;
    #pragma unroll 2
    for (int e4 = 0; e4 < 16; ++e4) {
        float w0 = wb[(e4 * 4 + 0) * 64 + lane];
        float w1 = wb[(e4 * 4 + 1) * 64 + lane];
        float w2 = wb[(e4 * 4 + 2) * 64 + lane];
        float w3 = wb[(e4 * 4 + 3) * 64 + lane];
        #pragma unroll
        for (int r = 0; r < 16; ++r) {
            float4 hv = *(const float4*)&h_sh[half * 16 + r][e4 * 4]; // uniform b128
            a[r] = fmaf(hv.x, w0, a[r]);
            a[r] = fmaf(hv.y, w1, a[r]);
            a[r] = fmaf(hv.z, w2, a[r]);
            a[r] = fmaf(hv.w, w3, a[r]);
        }
    }

    #pragma unroll
    for (int r = 0; r < 16; ++r) {
        int kl  = half * 16 + r;
        int row = rb0 + kl;
        unsigned short hb = f2bf(a[r]);
        float hf = bf2f(hb);
        hp[((size_t)head * N_TOK + row) * 64 + lane] = hb;
        int p = kperm(row & 63);              // halves write disjoint even/odd
        vt[head][(p >> 3) & 3][lane][p & 7] = hb;
        float s = hf * hf;
        #pragma unroll
        for (int off = 32; off > 0; off >>= 1) s += __shfl_xor(s, off);
        if (lane == 0) ssq2[head * N_TOK + row] = s * L2E2;
    }
    __syncthreads();

    // ---- write Vf coalesced: 1024 chunks of 16B, 2 per thread ----
    const int kgbase = (rb0 & 32) ? 4 : 0;
    #pragma unroll
    for (int i = 0; i < 2; ++i) {
        int c  = threadIdx.x + 512 * i;
        int hc = c >> 8, rem = c & 255;
        int kg = rem >> 6, d = rem & 63;
        short8 v = *(const short8*)&vt[hc][kg][d][0];
        *(short8*)&Vf[(((size_t)hc * (N_TOK / 8) + (rb0 >> 6) * 8 + kgbase + kg) * 64
                       + d) * 8] = v;
    }
}

// ---------------------------------------------------------------------------
// Flash distance-attention: r8 hot loop (proven 173 µs no-spill) + SOFTWARE-
// PIPELINED half-A K prefetch. Model: per-wave serial time ~13K cyc/ktile vs
// ~1.6K issue — the top-of-loop K load is the largest un-hidden latency
// (L2 ~200-400 cyc; previous tile's work is drained by then). The accS-split
// leaves a 16-reg window during PV (accS dead): load kt+1's half-A frags
// there, so next iteration's first 8 MFMAs fire immediately. Peak regs ~124
// <= 128 -> 4 waves/SIMD (pow2 allocation: 64/128/256 are the only steps).
// nsplit=4 (ktps=32): halves Og/Lg bytes vs r8. Max logit 0 (diagonal) -> no
// online rescaling. p = exp2(-sqrt(sq')); P packed bf16 pairs (kperm); O bf16.
// Grid (16 combos, 64 q-blocks); combo%8 -> one head per XCD.
// ---------------------------------------------------------------------------
__global__ __launch_bounds__(256, 4) void flash_kernel(
    const unsigned short* __restrict__ hp, const unsigned short* __restrict__ Vf,
    const float* __restrict__ ssq2, unsigned short* __restrict__ Og,
    float* __restrict__ Lg)
{
    const int head  = blockIdx.x & 3;        // combo = split*NHEADS+head
    const int split = blockIdx.x >> 2;
    const int q0    = blockIdx.y * 128;
    const int w     = threadIdx.x >> 6;
    const int lane  = threadIdx.x & 63;
    const int col   = lane & 15;
    const int quad  = lane >> 4;

    __shared__ __align__(16) unsigned short Psh[4][2][16][72];

    const unsigned short* hpH = hp + head * (N_TOK * 64);
    const unsigned short* VfH = Vf + head * (N_TOK * 64);
    const float* ssqH = ssq2 + head * N_TOK;

    const int rb = q0 + w * 32;              // this wave's 32 q-rows

    short8 aQ[2][2];
    float ssqn2[2][4];
    #pragma unroll
    for (int s = 0; s < 2; ++s) {
        const unsigned short* qrow = hpH + (rb + s * 16 + col) * 64;
        aQ[s][0] = *(const short8*)(qrow + quad * 8);
        aQ[s][1] = *(const short8*)(qrow + 32 + quad * 8);
        #pragma unroll
        for (int r = 0; r < 4; ++r)
            ssqn2[s][r] = ssqH[rb + s * 16 + quad * 4 + r];
    }

    const f32x4 zero4 = {0.f, 0.f, 0.f, 0.f};
    f32x4 accO[2][4] = {{zero4, zero4, zero4, zero4}, {zero4, zero4, zero4, zero4}};
    f32x4 accL[2] = {zero4, zero4};
    const short8 ones = {16256,16256,16256,16256,16256,16256,16256,16256}; // bf16 1.0
    const float NEG2L2 = -2.0f * L2E2;

    const int ktps = N_TOK / 64 / NSPLIT;    // 32
    const int kt0  = split * ktps;
    const int ktend = kt0 + ktps;

    // prime the software pipeline: half-A K frags for the first tile
    short8 kA[4];
    {
        const unsigned short* kb0 = hpH + kt0 * 4096;
        #pragma unroll
        for (int nt = 0; nt < 2; ++nt) {
            const unsigned short* kr = kb0 + (nt * 16 + col) * 64 + quad * 8;
            kA[nt * 2 + 0] = *(const short8*)kr;
            kA[nt * 2 + 1] = *(const short8*)(kr + 32);
        }
    }

    #pragma unroll 1
    for (int kt = kt0; kt < ktend; ++kt) {
        const unsigned short* kb = hpH + kt * 4096;
        const unsigned short* vb = VfH + kt * 4096;

        float sm2[4];
        #pragma unroll
        for (int nt = 0; nt < 4; ++nt) sm2[nt] = ssqH[kt * 64 + nt * 16 + col];

        // ---- half A: S for keys 0..31 — K frags already in registers ----
        f32x4 aSA[2][2] = {{zero4, zero4}, {zero4, zero4}};
        #pragma unroll
        for (int nt = 0; nt < 2; ++nt) {
            aSA[0][nt] = __builtin_amdgcn_mfma_f32_16x16x32_bf16(aQ[0][0], kA[nt * 2 + 0], aSA[0][nt], 0, 0, 0);
            aSA[0][nt] = __builtin_amdgcn_mfma_f32_16x16x32_bf16(aQ[0][1], kA[nt * 2 + 1], aSA[0][nt], 0, 0, 0);
            aSA[1][nt] = __builtin_amdgcn_mfma_f32_16x16x32_bf16(aQ[1][0], kA[nt * 2 + 0], aSA[1][nt], 0, 0, 0);
            aSA[1][nt] = __builtin_amdgcn_mfma_f32_16x16x32_bf16(aQ[1][1], kA[nt * 2 + 1], aSA[1][nt], 0, 0, 0);
        }

        // half-B K loads issued here: covered by softmax-A below (kA regs
        // are dead after the MFMAs above — reuse window, no extra pressure)
        short8 kB[4];
        #pragma unroll
        for (int nt = 0; nt < 2; ++nt) {
            const unsigned short* kr = kb + ((nt + 2) * 16 + col) * 64 + quad * 8;
            kB[nt * 2 + 0] = *(const short8*)kr;
            kB[nt * 2 + 1] = *(const short8*)(kr + 32);
        }

        // softmax A -> write d0 (cols 0..31); aSA dies here
        #pragma unroll
        for (int s = 0; s < 2; ++s) {
            float pf0[4], pf1[4];
            #pragma unroll
            for (int r = 0; r < 4; ++r) {
                float sq0 = fmaf(aSA[s][0][r], NEG2L2, ssqn2[s][r] + sm2[0]);
                pf0[r] = __builtin_amdgcn_exp2f(-__builtin_amdgcn_sqrtf(fmaxf(sq0, 0.f)));
                float sq1 = fmaf(aSA[s][1][r], NEG2L2, ssqn2[s][r] + sm2[1]);
                pf1[r] = __builtin_amdgcn_exp2f(-__builtin_amdgcn_sqrtf(fmaxf(sq1, 0.f)));
            }
            #pragma unroll
            for (int r = 0; r < 4; ++r) {
                unsigned int d0 = __builtin_amdgcn_perm(__float_as_uint(pf1[r]),
                                                        __float_as_uint(pf0[r]), 0x07060302u);
                *(unsigned int*)&Psh[w][s][quad * 4 + r][2 * col] = d0;
            }
        }

        // ---- half B: S for keys 32..63 ----
        f32x4 aSB[2][2] = {{zero4, zero4}, {zero4, zero4}};
        #pragma unroll
        for (int nt = 0; nt < 2; ++nt) {
            aSB[0][nt] = __builtin_amdgcn_mfma_f32_16x16x32_bf16(aQ[0][0], kB[nt * 2 + 0], aSB[0][nt], 0, 0, 0);
            aSB[0][nt] = __builtin_amdgcn_mfma_f32_16x16x32_bf16(aQ[0][1], kB[nt * 2 + 1], aSB[0][nt], 0, 0, 0);
            aSB[1][nt] = __builtin_amdgcn_mfma_f32_16x16x32_bf16(aQ[1][0], kB[nt * 2 + 0], aSB[1][nt], 0, 0, 0);
            aSB[1][nt] = __builtin_amdgcn_mfma_f32_16x16x32_bf16(aQ[1][1], kB[nt * 2 + 1], aSB[1][nt], 0, 0, 0);
        }

        // bV for c=0 issued here: latency covered by softmax-B (16 regs only)
        short8 bV0[4];
        #pragma unroll
        for (int dt = 0; dt < 4; ++dt)
            bV0[dt] = *(const short8*)(vb + (quad * 64 + dt * 16 + col) * 8);

        // softmax B -> write d1 (cols 32..63)
        #pragma unroll
        for (int s = 0; s < 2; ++s) {
            float pf2[4], pf3[4];
            #pragma unroll
            for (int r = 0; r < 4; ++r) {
                float sq2 = fmaf(aSB[s][0][r], NEG2L2, ssqn2[s][r] + sm2[2]);
                pf2[r] = __builtin_amdgcn_exp2f(-__builtin_amdgcn_sqrtf(fmaxf(sq2, 0.f)));
                float sq3 = fmaf(aSB[s][1][r], NEG2L2, ssqn2[s][r] + sm2[3]);
                pf3[r] = __builtin_amdgcn_exp2f(-__builtin_amdgcn_sqrtf(fmaxf(sq3, 0.f)));
            }
            #pragma unroll
            for (int r = 0; r < 4; ++r) {
                unsigned int d1 = __builtin_amdgcn_perm(__float_as_uint(pf3[r]),
                                                        __float_as_uint(pf2[r]), 0x07060302u);
                *(unsigned int*)&Psh[w][s][quad * 4 + r][32 + 2 * col] = d1;
            }
            // diag tile: force p=1.0 exactly
            int r0 = rb + s * 16;
            if (kt == (r0 >> 6) && lane < 16) {
                int t = (r0 >> 4) & 3;
                Psh[w][s][lane][((t & 2) << 4) + 2 * lane + (t & 1)] = 0x3F80;
            }
        }

        // ---- PV c=0: aP reads; prefetch next tile's half-A K + bV1 here
        //      (aSA/aSB dead -> register window; covered by 10 MFMAs) ----
        {
            const int ktn = (kt + 1 < ktend) ? kt + 1 : kt0;
            const unsigned short* kbn = hpH + ktn * 4096;

            short8 aP0 = *(const short8*)&Psh[w][0][col][quad * 8];
            short8 aP1 = *(const short8*)&Psh[w][1][col][quad * 8];
            short8 bV1[4];
            #pragma unroll
            for (int dt = 0; dt < 4; ++dt)
                bV1[dt] = *(const short8*)(vb + ((4 + quad) * 64 + dt * 16 + col) * 8);
            #pragma unroll
            for (int nt = 0; nt < 2; ++nt) {
                const unsigned short* kr = kbn + (nt * 16 + col) * 64 + quad * 8;
                kA[nt * 2 + 0] = *(const short8*)kr;
                kA[nt * 2 + 1] = *(const short8*)(kr + 32);
            }
            accL[0] = __builtin_amdgcn_mfma_f32_16x16x32_bf16(aP0, ones, accL[0], 0, 0, 0);
            accL[1] = __builtin_amdgcn_mfma_f32_16x16x32_bf16(aP1, ones, accL[1], 0, 0, 0);
            #pragma unroll
            for (int dt = 0; dt < 4; ++dt) {
                accO[0][dt] = __builtin_amdgcn_mfma_f32_16x16x32_bf16(aP0, bV0[dt], accO[0][dt], 0, 0, 0);
                accO[1][dt] = __builtin_amdgcn_mfma_f32_16x16x32_bf16(aP1, bV0[dt], accO[1][dt], 0, 0, 0);
            }
            // ---- PV c=1 ----
            short8 aP0b = *(const short8*)&Psh[w][0][col][32 + quad * 8];
            short8 aP1b = *(const short8*)&Psh[w][1][col][32 + quad * 8];
            accL[0] = __builtin_amdgcn_mfma_f32_16x16x32_bf16(aP0b, ones, accL[0], 0, 0, 0);
            accL[1] = __builtin_amdgcn_mfma_f32_16x16x32_bf16(aP1b, ones, accL[1], 0, 0, 0);
            #pragma unroll
            for (int dt = 0; dt < 4; ++dt) {
                accO[0][dt] = __builtin_amdgcn_mfma_f32_16x16x32_bf16(aP0b, bV1[dt], accO[0][dt], 0, 0, 0);
                accO[1][dt] = __builtin_amdgcn_mfma_f32_16x16x32_bf16(aP1b, bV1[dt], accO[1][dt], 0, 0, 0);
            }
        }
    }

    // ---- epilogue: unnormalized O (bf16) and l (f32) for this split ----
    unsigned short* og = Og + (size_t)(split * NHEADS + head) * N_TOK * 64;
    float* lg = Lg + (size_t)(split * NHEADS + head) * N_TOK;
    #pragma unroll
    for (int s = 0; s < 2; ++s)
        #pragma unroll
        for (int r = 0; r < 4; ++r) {
            int row = rb + s * 16 + quad * 4 + r;
            #pragma unroll
            for (int dt = 0; dt < 4; ++dt)
                og[row * 64 + dt * 16 + col] = f2bf(accO[s][dt][r]);
            if (col == 0) lg[row] = accL[s][r];
        }
}

// ---------------------------------------------------------------------------
// Combine: merge NSPLIT splits, head-softmax mix, layernorm, FC. Wave per row.
// ---------------------------------------------------------------------------
__global__ __launch_bounds__(256) void combine_kernel(
    const unsigned short* __restrict__ Og, const float* __restrict__ Lg,
    const float* __restrict__ attn_w, const float* __restrict__ gamma,
    const float* __restrict__ beta, const float* __restrict__ fc_w,
    const float* __restrict__ fc_b, float* __restrict__ out)
{
    const int lane = threadIdx.x & 63;
    const int ty   = threadIdx.x >> 6;
    const int row  = blockIdx.x * 4 + ty;

    float a0 = attn_w[0], a1 = attn_w[1], a2 = attn_w[2], a3 = attn_w[3];
    float m = fmaxf(fmaxf(a0, a1), fmaxf(a2, a3));
    float e0 = __expf(a0 - m), e1 = __expf(a1 - m), e2 = __expf(a2 - m), e3 = __expf(a3 - m);
    float inv = 1.f / (e0 + e1 + e2 + e3);
    float aw[4] = {e0 * inv, e1 * inv, e2 * inv, e3 * inv};

    float c = 0.f;
    #pragma unroll
    for (int hh = 0; hh < NHEADS; ++hh) {
        float l = 0.f, o = 0.f;
        #pragma unroll
        for (int s = 0; s < NSPLIT; ++s) {
            l += Lg[(s * NHEADS + hh) * N_TOK + row];
            o += bf2f(Og[(size_t)((s * NHEADS + hh) * N_TOK + row) * 64 + lane]);
        }
        c += aw[hh] * o * __builtin_amdgcn_rcpf(l);
    }

    float s = c;
    #pragma unroll
    for (int off = 32; off > 0; off >>= 1) s += __shfl_xor(s, off);
    float mu = s * (1.f / 64.f);
    float d = c - mu;
    float v = d * d;
    #pragma unroll
    for (int off = 32; off > 0; off >>= 1) v += __shfl_xor(v, off);
    float normed = d * rsqrtf(v * (1.f / 64.f) + LN_EPS) * gamma[lane] + beta[lane];

    float lg[N_CLS];
    #pragma unroll
    for (int cc = 0; cc < N_CLS; ++cc) {
        float p = normed * fc_w[lane * N_CLS + cc];
        #pragma unroll
        for (int off = 32; off > 0; off >>= 1) p += __shfl_xor(p, off);
        lg[cc] = p;
    }
    if (lane == 0) {
        #pragma unroll
        for (int cc = 0; cc < N_CLS; ++cc)
            out[row * N_CLS + cc] = lg[cc] + fc_b[cc];
    }
}

// ---------------------------------------------------------------------------
extern "C" void kernel_launch(void* const* d_in, const int* in_sizes, int n_in,
                              void* d_out, int out_size, void* d_ws, size_t ws_size,
                              hipStream_t stream)
{
    const float* x      = (const float*)d_in[0];
    const float* proj_w = (const float*)d_in[1];
    const float* proj_b = (const float*)d_in[2];
    const float* head_w = (const float*)d_in[3];
    const float* head_b = (const float*)d_in[4];
    const float* attn_w = (const float*)d_in[5];
    const float* gamma  = (const float*)d_in[6];
    const float* beta   = (const float*)d_in[7];
    const float* fc_w   = (const float*)d_in[8];
    const float* fc_b   = (const float*)d_in[9];
    float* out = (float*)d_out;

    char* ws = (char*)d_ws;
    // ws layout (bytes):
    //   hp   bf16 [4][8192][64]        @ 0          (4 MB)
    //   Vf   bf16 [4][1024][64][8]     @ 4 MB       (4 MB, key-permuted)
    //   ssq2 f32  [4][8192]            @ 8 MB       (128 KB)
    //   Og   bf16 [4][4][8192][64]     @ 8M+128K    (16 MB)
    //   Lg   f32  [4][4][8192]         @ 24M+128K   (512 KB)
    unsigned short* hp = (unsigned short*)(ws);
    unsigned short* Vf = (unsigned short*)(ws + (4u << 20));
    float* ssq2 = (float*)(ws + (8u << 20));
    unsigned short* Og = (unsigned short*)(ws + (8u << 20) + (128u << 10));
    float* Lg   = (float*)(ws + (24u << 20) + (128u << 10));

    stage1_kernel<<<N_TOK / 32, 512, 0, stream>>>(x, proj_w, proj_b, head_w, head_b,
                                                  hp, Vf, ssq2);
    dim3 g2(NHEADS * NSPLIT, N_TOK / 128);  // combo fastest -> one head per XCD
    flash_kernel<<<g2, 256, 0, stream>>>(hp, Vf, ssq2, Og, Lg);
    combine_kernel<<<N_TOK / 4, 256, 0, stream>>>(Og, Lg, attn_w, gamma, beta,
                                                  fc_w, fc_b, out);
}